// Round 12
// baseline (206.657 us; speedup 1.0000x reference)
//
#include <hip/hip_runtime.h>
#include <hip/hip_bf16.h>
#include <cmath>

#define NHEADS 32
#define DIM 128
#define SPLITS 16
#define TILE 32
#define KSPLIT 16
#define QKV_N 4352
#define HID 4096
#define VSTR 132   // VL row stride (ushorts): conflict-free strided b16 reads

typedef __attribute__((ext_vector_type(4))) float f32x4;
typedef __attribute__((ext_vector_type(8))) short short8i;
typedef __attribute__((ext_vector_type(4))) short short4i;

__device__ __forceinline__ unsigned short f2bf(float x) {
  __hip_bfloat16 h = __float2bfloat16(x);   // RNE; HW cvt
  return *reinterpret_cast<unsigned short*>(&h);
}
__device__ __forceinline__ unsigned int pk2bf(float lo, float hi) {
  return (unsigned)f2bf(lo) | ((unsigned)f2bf(hi) << 16);
}
__device__ __forceinline__ float bf2f(unsigned short u) {
  unsigned int b = ((unsigned int)u) << 16;
  return __uint_as_float(b);
}

__device__ __forceinline__ f32x4 mfma16bf16(short4i a, short4i b, f32x4 c) {
#if __has_builtin(__builtin_amdgcn_mfma_f32_16x16x16bf16_1k)
  return __builtin_amdgcn_mfma_f32_16x16x16bf16_1k(a, b, c, 0, 0, 0);
#else
  asm volatile("v_mfma_f32_16x16x16_bf16 %0, %1, %2, %0"
               : "+v"(c) : "v"(a), "v"(b));
  return c;
#endif
}

// C[64,N] partials = A[64,K] @ W[K,N] via bf16 MFMA, fused fp32->bf16 convert.
// grid=(N/64, KSPLIT), block=256 (4 waves; wave w owns rows w*16..w*16+15).
__global__ __launch_bounds__(256, 4) void gemm64_mfma(
    const float* __restrict__ A, const float* __restrict__ W,
    float* __restrict__ P, int N, int K)
{
  __shared__ unsigned short Ab[64][40];   // bf16 A-tile [m][k]
  __shared__ unsigned short Wt[64][40];   // bf16 W-tile transposed [n][k]
  const int t = threadIdx.x;
  const int w = t >> 6, lane = t & 63;
  const int l4 = lane >> 4, l16 = lane & 15;
  const int n0 = blockIdx.x * 64;
  const int KS = K / KSPLIT;
  const int kbase = blockIdx.y * KS;

  const int ar = t >> 2, akq = t & 3;     // A staging: row 0..63, k-oct 0..3
  const int bn = t & 63, bkq = t >> 6;    // B staging: n 0..63, k-oct 0..3

  f32x4 acc[4];
#pragma unroll
  for (int i = 0; i < 4; ++i) acc[i] = (f32x4){0.f, 0.f, 0.f, 0.f};

  float4 a0, a1;
  float bw[8];

#define GLOAD(KC)                                                          \
  {                                                                        \
    const float* ap = A + (size_t)ar * K + kbase + (KC) + akq * 8;         \
    a0 = *(const float4*)ap;                                               \
    a1 = *(const float4*)(ap + 4);                                         \
    const float* wp = W + (size_t)(kbase + (KC) + bkq * 8) * N + n0 + bn;  \
    _Pragma("unroll")                                                      \
    for (int j = 0; j < 8; ++j) bw[j] = wp[(size_t)j * N];                 \
  }

#define SWRITE                                                             \
  {                                                                        \
    unsigned int ua[4] = {pk2bf(a0.x, a0.y), pk2bf(a0.z, a0.w),            \
                          pk2bf(a1.x, a1.y), pk2bf(a1.z, a1.w)};           \
    *(float4*)&Ab[ar][akq * 8] = *(float4*)ua;                             \
    unsigned int ub[4] = {pk2bf(bw[0], bw[1]), pk2bf(bw[2], bw[3]),        \
                          pk2bf(bw[4], bw[5]), pk2bf(bw[6], bw[7])};       \
    *(float4*)&Wt[bn][bkq * 8] = *(float4*)ub;                             \
  }

  GLOAD(0);
  SWRITE;
  __syncthreads();

  for (int kc = 0; kc < KS; kc += 32) {
    const bool pre = (kc + 32 < KS);
    if (pre) GLOAD(kc + 32);

    const short8i af = *(const short8i*)&Ab[w * 16 + l16][l4 * 8];
#pragma unroll
    for (int nt = 0; nt < 4; ++nt) {
      const short8i bf = *(const short8i*)&Wt[nt * 16 + l16][l4 * 8];
      acc[nt] = __builtin_amdgcn_mfma_f32_16x16x32_bf16(af, bf, acc[nt], 0, 0, 0);
    }

    __syncthreads();
    if (pre) {
      SWRITE;
      __syncthreads();
    }
  }

  float* base = P + (size_t)blockIdx.y * 64 * N + n0;
#pragma unroll
  for (int nt = 0; nt < 4; ++nt)
#pragma unroll
    for (int r = 0; r < 4; ++r)
      base[(size_t)(w * 16 + l4 * 4 + r) * N + nt * 16 + l16] = acc[nt][r];
#undef GLOAD
#undef SWRITE
}

__global__ __launch_bounds__(256) void reduce_parts(
    const float* __restrict__ P, float* __restrict__ C, int total)
{
  const int i = (blockIdx.x * 256 + threadIdx.x) * 4;
  if (i >= total) return;
  float4 s = *(const float4*)(P + i);
#pragma unroll
  for (int k = 1; k < KSPLIT; ++k) {
    const float4 v = *(const float4*)(P + (size_t)k * total + i);
    s.x += v.x; s.y += v.y; s.z += v.z; s.w += v.w;
  }
  *(float4*)(C + i) = s;
}

// RoPE in place on q (32 heads) and k row of qkv. grid=64, block=256
__global__ __launch_bounds__(256) void rope_kernel(
    float* __restrict__ qkv, const int* __restrict__ positions)
{
  const int b = blockIdx.x;
  float* row = qkv + (size_t)b * QKV_N;
  const float pos = (float)positions[b];
  for (int it = threadIdx.x; it < 33 * 64; it += 256) {
    const int r = it >> 6, i = it & 63;
    float* x = row + (r < 32 ? r * DIM : HID);
    const float ex = (float)(2 * i) * (1.0f / 128.0f);
    const float inv = 1.0f / powf(10000.0f, ex);
    const float ang = pos * inv;
    const float c = cosf(ang), sn = sinf(ang);
    const float x1 = x[i], x2 = x[i + 64];
    x[i]      = x1 * c - x2 * sn;
    x[i + 64] = x2 * c + x1 * sn;
  }
}

// MFMA flash-decoding attention, all-streaming global loads.
// grid=(64, SPLITS), block=128 (2 waves; wave w owns head-group w, full tile).
// K: LDS XOR-swizzled bf16; V: LDS LINEAR [pos][od] bf16 (stride VSTR).
// Both K and V stream contiguous 512B rows from global (no gathers).
// No cross-wave reduction: each wave's 16 heads are disjoint outputs.
__global__ __launch_bounds__(128, 3) void attn_kernel(
    const float* __restrict__ qkv,
    const float* __restrict__ k_cache, const float* __restrict__ v_cache,
    const int* __restrict__ block_tables, const int* __restrict__ context_lens,
    float* __restrict__ pl, unsigned short* __restrict__ pacc)
{
  const int b = blockIdx.x, s = blockIdx.y;
  const int t = threadIdx.x;            // 0..127
  const int w = t >> 6, lane = t & 63;  // 2 waves
  const int l4 = lane >> 4, l16 = lane & 15;
  const int ctx = context_lens[b];
  const int pos = ctx - 1;
  const int chunk = (ctx + SPLITS - 1) / SPLITS;
  const int start = s * chunk;
  const int end = min(start + chunk, ctx);
  const int nt = (end > start) ? ((end - start + TILE - 1) / TILE) : 0;

  __shared__ unsigned short KbU[32 * 128];   // 8 KB bf16 K, XOR-swizzled 16B units
  __shared__ unsigned short VL[TILE][VSTR];  // 8.25 KB bf16 V linear [pos][od]
  __shared__ int bt_lds[20];

  const float* qbase = qkv + (size_t)b * QKV_N;
  const int bt0 = start >> 4;
  if (t < 20) {
    const int idx = bt0 + t;
    bt_lds[t] = (idx < 256) ? block_tables[b * 256 + idx] : 0;
  }

  // Q fragment (B-operand of swapped QK^T): head-group hq = w
  const int hq = w;
  const float scale = 0.08838834764831845f;  // 1/sqrt(128)
  short8i qf[4];
  {
    const float* qp0 = qbase + (hq * 16 + l16) * DIM + l4 * 8;
#pragma unroll
    for (int ks = 0; ks < 4; ++ks) {
      const float4 a = *(const float4*)(qp0 + ks * 32);
      const float4 c = *(const float4*)(qp0 + ks * 32 + 4);
      union { unsigned int u[4]; short8i v; } qc;
      qc.u[0] = pk2bf(a.x * scale, a.y * scale);
      qc.u[1] = pk2bf(a.z * scale, a.w * scale);
      qc.u[2] = pk2bf(c.x * scale, c.y * scale);
      qc.u[3] = pk2bf(c.z * scale, c.w * scale);
      qf[ks] = qc.v;
    }
  }

  f32x4 o2[8];
#pragma unroll
  for (int i = 0; i < 8; ++i) o2[i] = (f32x4){0.f, 0.f, 0.f, 0.f};
  float lh = 0.f;

  const int tcol = t & 31;   // float4 column within a row
  const int tsub = t >> 5;   // 0..3: row sub-index
  float4 kreg[8], vreg[8];

  // Streaming loads: thread owns rows {j*4 + tsub}; K and V share the row
  // pointer (one blk lookup), each row read as contiguous 512B across 32 lanes.
#define LOADREGS(T0)                                                     \
  {                                                                      \
    _Pragma("unroll")                                                    \
    for (int j = 0; j < 8; ++j) {                                        \
      int gp_ = (T0) + j * 4 + tsub;                                     \
      if (gp_ > pos) gp_ = pos;                                          \
      const float *kp, *vp;                                              \
      if (gp_ == pos) { kp = qbase + HID; vp = qbase + HID + DIM; }      \
      else {                                                             \
        const int blk = bt_lds[(gp_ >> 4) - bt0];                        \
        const size_t cidx = ((size_t)blk * 16 + (gp_ & 15)) * DIM;       \
        kp = k_cache + cidx; vp = v_cache + cidx;                        \
      }                                                                  \
      kreg[j] = ((const float4*)kp)[tcol];                               \
      vreg[j] = ((const float4*)vp)[tcol];                               \
    }                                                                    \
  }

#define WRITE_TILE                                                                  \
  {                                                                                 \
    _Pragma("unroll")                                                               \
    for (int j = 0; j < 8; ++j) {                                                   \
      const int row = j * 4 + tsub;                                                 \
      const int up = (tcol >> 1) ^ (row & 15);                                      \
      unsigned int* kd = (unsigned int*)&KbU[row * 128 + up * 8 + (tcol & 1) * 4];  \
      kd[0] = pk2bf(kreg[j].x, kreg[j].y);                                          \
      kd[1] = pk2bf(kreg[j].z, kreg[j].w);                                          \
      unsigned int* vd = (unsigned int*)&VL[row][tcol * 4];                         \
      vd[0] = pk2bf(vreg[j].x, vreg[j].y);                                          \
      vd[1] = pk2bf(vreg[j].z, vreg[j].w);                                          \
    }                                                                               \
  }

  if (nt > 0) {
    __syncthreads();             // bt_lds visible
    LOADREGS(start);
    WRITE_TILE;
    __syncthreads();

    for (int it = 0; it < nt; ++it) {
      const int t0 = start + it * TILE;
      const bool pre = (it + 1 < nt);
      if (pre) LOADREGS(t0 + TILE);    // vmem in flight under compute (T14)

      short4i pf[2];
#pragma unroll
      for (int pg = 0; pg < 2; ++pg) {
        // ---- QK^T: D[pos,head] for 16 positions ----
        f32x4 accs = {0.f, 0.f, 0.f, 0.f};
        const int rowK = pg * 16 + l16;
#pragma unroll
        for (int ks = 0; ks < 4; ++ks) {
          const int up = (l4 + ks * 4) ^ l16;
          const short8i kf = *(const short8i*)&KbU[rowK * 128 + up * 8];
          accs = __builtin_amdgcn_mfma_f32_16x16x32_bf16(kf, qf[ks], accs, 0, 0, 0);
        }
        // ---- exp (no max), mask, denom, pack P as PV A-frag ----
        const int pb_ = t0 + pg * 16 + l4 * 4;
        const float p0 = (pb_ + 0 < end) ? __expf(accs[0]) : 0.f;
        const float p1 = (pb_ + 1 < end) ? __expf(accs[1]) : 0.f;
        const float p2 = (pb_ + 2 < end) ? __expf(accs[2]) : 0.f;
        const float p3 = (pb_ + 3 < end) ? __expf(accs[3]) : 0.f;
        lh += (p0 + p1) + (p2 + p3);
        union { unsigned int u[2]; short4i v; } pc;
        pc.u[0] = pk2bf(p0, p1);
        pc.u[1] = pk2bf(p2, p3);
        pf[pg] = pc.v;
      }

      // ---- PV: o2[ob] += P * V, both 16-pos groups chained over k ----
#pragma unroll
      for (int ob = 0; ob < 8; ++ob) {
#pragma unroll
        for (int pg = 0; pg < 2; ++pg) {
          union { unsigned short su[4]; short4i v; } vc;
#pragma unroll
          for (int j = 0; j < 4; ++j)
            vc.su[j] = VL[pg * 16 + l4 * 4 + j][ob * 16 + l16];
          o2[ob] = mfma16bf16(pf[pg], vc.v, o2[ob]);
        }
      }

      if (pre) {
        __syncthreads();           // all waves done reading KbU/VL
        WRITE_TILE;                // stage next tile (waits own vmcnt)
        __syncthreads();           // writes visible
      }
    }
  }

  // ---- end of split: reduce denom over l4 groups (per head l16) ----
  float lhr = lh;
  lhr += __shfl_xor(lhr, 16);
  lhr += __shfl_xor(lhr, 32);

  const size_t sbase = (size_t)(b * SPLITS + s) * NHEADS + hq * 16;
#pragma unroll
  for (int ob = 0; ob < 8; ++ob) {
    pacc[(sbase + l4 * 4 + 0) * DIM + ob * 16 + l16] = f2bf(o2[ob][0]);
    pacc[(sbase + l4 * 4 + 1) * DIM + ob * 16 + l16] = f2bf(o2[ob][1]);
    pacc[(sbase + l4 * 4 + 2) * DIM + ob * 16 + l16] = f2bf(o2[ob][2]);
    pacc[(sbase + l4 * 4 + 3) * DIM + ob * 16 + l16] = f2bf(o2[ob][3]);
  }
  if (lane < 16) pl[sbase + lane] = lhr;
#undef LOADREGS
#undef WRITE_TILE
}

// combine partials -> attn[b][h*128+d]. grid=2048, block=128.
// No-max softmax => equal split weights: out = sum(pacc)/sum(pl).
__global__ __launch_bounds__(128) void combine_kernel(
    const float* __restrict__ pl, const unsigned short* __restrict__ pacc,
    float* __restrict__ attn)
{
  const int bh = blockIdx.x;
  const int b = bh >> 5, h = bh & 31;
  const int d = threadIdx.x;
  float L = 0.f, o = 0.f;
#pragma unroll
  for (int s = 0; s < SPLITS; ++s) {
    const size_t idx = (size_t)(b * SPLITS + s) * NHEADS + h;
    L += pl[idx];
    o += bf2f(pacc[idx * DIM + d]);
  }
  attn[(size_t)b * HID + h * DIM + d] = o / L;
}

extern "C" void kernel_launch(void* const* d_in, const int* in_sizes, int n_in,
                              void* d_out, int out_size, void* d_ws, size_t ws_size,
                              hipStream_t stream) {
  const float* hidden   = (const float*)d_in[0];
  const float* wqkv     = (const float*)d_in[1];
  const float* wdense   = (const float*)d_in[2];
  const float* k_cache  = (const float*)d_in[3];
  const float* v_cache  = (const float*)d_in[4];
  const int* positions    = (const int*)d_in[5];   // integer inputs arrive as int32
  const int* block_tables = (const int*)d_in[6];
  const int* context_lens = (const int*)d_in[7];
  float* out = (float*)d_out;

  float* qkv  = (float*)d_ws;                 // 64*4352
  float* attn = qkv + 64 * QKV_N;             // 64*4096
  // union region: gp (GEMM partials, 16*64*4352 = 4.46M fl) aliases
  // pacc (bf16, 64*16*32*128 = 2.10M fl-equiv) + pl (32K fl); disjoint lifetimes.
  float* un   = attn + 64 * HID;
  float* gp   = un;
  unsigned short* pacc = (unsigned short*)un;
  float* pl   = un + (size_t)64 * SPLITS * NHEADS * DIM / 2;

  // 1) qkv = hidden @ wqkv  (bf16 MFMA, fused convert)
  gemm64_mfma<<<dim3(QKV_N / 64, KSPLIT), 256, 0, stream>>>(hidden, wqkv, gp, QKV_N, HID);
  reduce_parts<<<(64 * QKV_N) / 1024, 256, 0, stream>>>(gp, qkv, 64 * QKV_N);
  // 2) RoPE on q and k
  rope_kernel<<<64, 256, 0, stream>>>(qkv, positions);
  // 3) attention (MFMA flash-decoding, streaming K+V, 2-wave blocks)
  attn_kernel<<<dim3(64, SPLITS), 128, 0, stream>>>(qkv, k_cache, v_cache,
                                                    block_tables, context_lens, pl, pacc);
  combine_kernel<<<64 * NHEADS, 128, 0, stream>>>(pl, pacc, attn);
  // 4) out = attn @ wdense  (bf16 MFMA, fused convert)
  gemm64_mfma<<<dim3(HID / 64, KSPLIT), 256, 0, stream>>>(attn, wdense, gp, HID, HID);
  reduce_parts<<<(64 * HID) / 1024, 256, 0, stream>>>(gp, out, 64 * HID);
}

// Round 13
// 109.214 us; speedup vs baseline: 1.8922x; 1.8922x over previous
//
#include <hip/hip_runtime.h>
#include <hip/hip_bf16.h>
#include <cmath>

#define NHEADS 32
#define DIM 128
#define SPLITS 16
#define TILE 32
#define KSPLIT 16
#define QKV_N 4352
#define HID 4096
#define VSTR 36    // V^T row stride (ushorts): 72B, 8-aligned -> b64 frag reads

typedef __attribute__((ext_vector_type(4))) float f32x4;
typedef __attribute__((ext_vector_type(8))) short short8i;
typedef __attribute__((ext_vector_type(4))) short short4i;

__device__ __forceinline__ unsigned short f2bf(float x) {
  __hip_bfloat16 h = __float2bfloat16(x);   // RNE; HW cvt
  return *reinterpret_cast<unsigned short*>(&h);
}
__device__ __forceinline__ unsigned int pk2bf(float lo, float hi) {
  return (unsigned)f2bf(lo) | ((unsigned)f2bf(hi) << 16);
}
__device__ __forceinline__ float bf2f(unsigned short u) {
  unsigned int b = ((unsigned int)u) << 16;
  return __uint_as_float(b);
}

__device__ __forceinline__ f32x4 mfma16bf16(short4i a, short4i b, f32x4 c) {
#if __has_builtin(__builtin_amdgcn_mfma_f32_16x16x16bf16_1k)
  return __builtin_amdgcn_mfma_f32_16x16x16bf16_1k(a, b, c, 0, 0, 0);
#else
  asm volatile("v_mfma_f32_16x16x16_bf16 %0, %1, %2, %0"
               : "+v"(c) : "v"(a), "v"(b));
  return c;
#endif
}

// C[64,N] partials = A[64,K] @ W[K,N] via bf16 MFMA, fused fp32->bf16 convert.
// grid=(N/64, KSPLIT), block=256 (4 waves; wave w owns rows w*16..w*16+15).
__global__ __launch_bounds__(256, 4) void gemm64_mfma(
    const float* __restrict__ A, const float* __restrict__ W,
    float* __restrict__ P, int N, int K)
{
  __shared__ unsigned short Ab[64][40];   // bf16 A-tile [m][k]
  __shared__ unsigned short Wt[64][40];   // bf16 W-tile transposed [n][k]
  const int t = threadIdx.x;
  const int w = t >> 6, lane = t & 63;
  const int l4 = lane >> 4, l16 = lane & 15;
  const int n0 = blockIdx.x * 64;
  const int KS = K / KSPLIT;
  const int kbase = blockIdx.y * KS;

  const int ar = t >> 2, akq = t & 3;     // A staging: row 0..63, k-oct 0..3
  const int bn = t & 63, bkq = t >> 6;    // B staging: n 0..63, k-oct 0..3

  f32x4 acc[4];
#pragma unroll
  for (int i = 0; i < 4; ++i) acc[i] = (f32x4){0.f, 0.f, 0.f, 0.f};

  float4 a0, a1;
  float bw[8];

#define GLOAD(KC)                                                          \
  {                                                                        \
    const float* ap = A + (size_t)ar * K + kbase + (KC) + akq * 8;         \
    a0 = *(const float4*)ap;                                               \
    a1 = *(const float4*)(ap + 4);                                         \
    const float* wp = W + (size_t)(kbase + (KC) + bkq * 8) * N + n0 + bn;  \
    _Pragma("unroll")                                                      \
    for (int j = 0; j < 8; ++j) bw[j] = wp[(size_t)j * N];                 \
  }

#define SWRITE                                                             \
  {                                                                        \
    unsigned int ua[4] = {pk2bf(a0.x, a0.y), pk2bf(a0.z, a0.w),            \
                          pk2bf(a1.x, a1.y), pk2bf(a1.z, a1.w)};           \
    *(float4*)&Ab[ar][akq * 8] = *(float4*)ua;                             \
    unsigned int ub[4] = {pk2bf(bw[0], bw[1]), pk2bf(bw[2], bw[3]),        \
                          pk2bf(bw[4], bw[5]), pk2bf(bw[6], bw[7])};       \
    *(float4*)&Wt[bn][bkq * 8] = *(float4*)ub;                             \
  }

  GLOAD(0);
  SWRITE;
  __syncthreads();

  for (int kc = 0; kc < KS; kc += 32) {
    const bool pre = (kc + 32 < KS);
    if (pre) GLOAD(kc + 32);

    const short8i af = *(const short8i*)&Ab[w * 16 + l16][l4 * 8];
#pragma unroll
    for (int nt = 0; nt < 4; ++nt) {
      const short8i bf = *(const short8i*)&Wt[nt * 16 + l16][l4 * 8];
      acc[nt] = __builtin_amdgcn_mfma_f32_16x16x32_bf16(af, bf, acc[nt], 0, 0, 0);
    }

    __syncthreads();
    if (pre) {
      SWRITE;
      __syncthreads();
    }
  }

  float* base = P + (size_t)blockIdx.y * 64 * N + n0;
#pragma unroll
  for (int nt = 0; nt < 4; ++nt)
#pragma unroll
    for (int r = 0; r < 4; ++r)
      base[(size_t)(w * 16 + l4 * 4 + r) * N + nt * 16 + l16] = acc[nt][r];
#undef GLOAD
#undef SWRITE
}

__global__ __launch_bounds__(256) void reduce_parts(
    const float* __restrict__ P, float* __restrict__ C, int total)
{
  const int i = (blockIdx.x * 256 + threadIdx.x) * 4;
  if (i >= total) return;
  float4 s = *(const float4*)(P + i);
#pragma unroll
  for (int k = 1; k < KSPLIT; ++k) {
    const float4 v = *(const float4*)(P + (size_t)k * total + i);
    s.x += v.x; s.y += v.y; s.z += v.z; s.w += v.w;
  }
  *(float4*)(C + i) = s;
}

// RoPE in place on q (32 heads) and k row of qkv. grid=64, block=256
__global__ __launch_bounds__(256) void rope_kernel(
    float* __restrict__ qkv, const int* __restrict__ positions)
{
  const int b = blockIdx.x;
  float* row = qkv + (size_t)b * QKV_N;
  const float pos = (float)positions[b];
  for (int it = threadIdx.x; it < 33 * 64; it += 256) {
    const int r = it >> 6, i = it & 63;
    float* x = row + (r < 32 ? r * DIM : HID);
    const float ex = (float)(2 * i) * (1.0f / 128.0f);
    const float inv = 1.0f / powf(10000.0f, ex);
    const float ang = pos * inv;
    const float c = cosf(ang), sn = sinf(ang);
    const float x1 = x[i], x2 = x[i + 64];
    x[i]      = x1 * c - x2 * sn;
    x[i + 64] = x2 * c + x1 * sn;
  }
}

// MFMA flash-decoding attention (R9 structure + dbuf/1-barrier + b64 V reads
// + global pq-partials). grid=(64, SPLITS), block=256
// (4 waves: hq=w>>1 head-16-block, pq=w&1 pos-16-block of the 32-tile).
__global__ __launch_bounds__(256, 4) void attn_kernel(
    const float* __restrict__ qkv,
    const float* __restrict__ k_cache, const float* __restrict__ v_cache,
    const int* __restrict__ block_tables, const int* __restrict__ context_lens,
    float* __restrict__ pl, unsigned short* __restrict__ pacc)
{
  const int b = blockIdx.x, s = blockIdx.y;
  const int t = threadIdx.x;
  const int w = t >> 6, lane = t & 63;
  const int hq = w >> 1, pq = w & 1;
  const int l4 = lane >> 4, l16 = lane & 15;
  const int ctx = context_lens[b];
  const int pos = ctx - 1;
  const int chunk = (ctx + SPLITS - 1) / SPLITS;
  const int start = s * chunk;
  const int end = min(start + chunk, ctx);
  const int nt = (end > start) ? ((end - start + TILE - 1) / TILE) : 0;

  __shared__ unsigned short KbU[2][32 * 128];   // 2x8 KB bf16 K, XOR-swizzled
  __shared__ unsigned short VtU[2][128 * VSTR]; // 2x9.2 KB bf16 V^T [od][pos]
  __shared__ int bt_lds[20];

  const float* qbase = qkv + (size_t)b * QKV_N;
  const int bt0 = start >> 4;
  if (t < 20) {
    const int idx = bt0 + t;
    bt_lds[t] = (idx < 256) ? block_tables[b * 256 + idx] : 0;
  }

  const float scale = 0.08838834764831845f;  // 1/sqrt(128)
  short8i qf[4];
  {
    const float* qp0 = qbase + (hq * 16 + l16) * DIM + l4 * 8;
#pragma unroll
    for (int ks = 0; ks < 4; ++ks) {
      const float4 a = *(const float4*)(qp0 + ks * 32);
      const float4 c = *(const float4*)(qp0 + ks * 32 + 4);
      union { unsigned int u[4]; short8i v; } qc;
      qc.u[0] = pk2bf(a.x * scale, a.y * scale);
      qc.u[1] = pk2bf(a.z * scale, a.w * scale);
      qc.u[2] = pk2bf(c.x * scale, c.y * scale);
      qc.u[3] = pk2bf(c.z * scale, c.w * scale);
      qf[ks] = qc.v;
    }
  }

  f32x4 o2[8];
#pragma unroll
  for (int i = 0; i < 8; ++i) o2[i] = (f32x4){0.f, 0.f, 0.f, 0.f};
  float lh = 0.f;

  float4 kreg[4], vreg[4];
  const int tk_sub = t >> 5;   // 0..7
  const int tk_col = t & 31;   // 0..31

#define LOADREGS(T0)                                                     \
  {                                                                      \
    _Pragma("unroll")                                                    \
    for (int j = 0; j < 4; ++j) {                                        \
      int gp_ = (T0) + j * 8 + tk_sub;                                   \
      if (gp_ > pos) gp_ = pos;                                          \
      const float* kp;                                                   \
      if (gp_ == pos) kp = qbase + HID;                                  \
      else {                                                             \
        const int blk = bt_lds[(gp_ >> 4) - bt0];                        \
        kp = k_cache + ((size_t)blk * 16 + (gp_ & 15)) * DIM;            \
      }                                                                  \
      kreg[j] = *(const float4*)(kp + tk_col * 4);                       \
    }                                                                    \
    int gv = (T0) + tk_col;                                              \
    if (gv > pos) gv = pos;                                              \
    const float* vp;                                                     \
    if (gv == pos) vp = qbase + HID + DIM;                               \
    else {                                                               \
      const int blk = bt_lds[(gv >> 4) - bt0];                           \
      vp = v_cache + ((size_t)blk * 16 + (gv & 15)) * DIM;               \
    }                                                                    \
    _Pragma("unroll")                                                    \
    for (int j = 0; j < 4; ++j)                                          \
      vreg[j] = *(const float4*)(vp + tk_sub * 16 + j * 4);              \
  }

#define WRITE_TILE(BUF)                                                                \
  {                                                                                    \
    _Pragma("unroll")                                                                  \
    for (int j = 0; j < 4; ++j) {                                                      \
      const int pl_ = j * 8 + tk_sub;                                                  \
      const int up = (tk_col >> 1) ^ (pl_ & 15);                                       \
      unsigned int* kd =                                                               \
          (unsigned int*)&KbU[BUF][pl_ * 128 + up * 8 + (tk_col & 1) * 4];             \
      kd[0] = pk2bf(kreg[j].x, kreg[j].y);                                             \
      kd[1] = pk2bf(kreg[j].z, kreg[j].w);                                             \
    }                                                                                  \
    _Pragma("unroll")                                                                  \
    for (int j = 0; j < 4; ++j) {                                                      \
      const int od0 = tk_sub * 16 + j * 4;                                             \
      VtU[BUF][(od0 + 0) * VSTR + tk_col] = f2bf(vreg[j].x);                           \
      VtU[BUF][(od0 + 1) * VSTR + tk_col] = f2bf(vreg[j].y);                           \
      VtU[BUF][(od0 + 2) * VSTR + tk_col] = f2bf(vreg[j].z);                           \
      VtU[BUF][(od0 + 3) * VSTR + tk_col] = f2bf(vreg[j].w);                           \
    }                                                                                  \
  }

  if (nt > 0) {
    __syncthreads();             // bt_lds visible
    LOADREGS(start);
    WRITE_TILE(0);

    for (int it = 0; it < nt; ++it) {
      const int t0 = start + it * TILE;
      const int cur = it & 1;
      const bool pre = (it + 1 < nt);
      if (pre) LOADREGS(t0 + TILE);   // issue next-tile loads early
      __syncthreads();                // buffer `cur` writes visible to all

      // ---- QK^T: D[pos,head] over this wave's quadrant ----
      f32x4 accs = {0.f, 0.f, 0.f, 0.f};
      const int rowK = pq * 16 + l16;
#pragma unroll
      for (int ks = 0; ks < 4; ++ks) {
        const int up = (l4 + ks * 4) ^ l16;
        const short8i kf = *(const short8i*)&KbU[cur][rowK * 128 + up * 8];
        accs = __builtin_amdgcn_mfma_f32_16x16x32_bf16(kf, qf[ks], accs, 0, 0, 0);
      }

      // ---- exp (no max), mask, per-lane denom, pack P as PV A-frag ----
      const int pb_ = t0 + pq * 16 + l4 * 4;
      const float p0 = (pb_ + 0 < end) ? __expf(accs[0]) : 0.f;
      const float p1 = (pb_ + 1 < end) ? __expf(accs[1]) : 0.f;
      const float p2 = (pb_ + 2 < end) ? __expf(accs[2]) : 0.f;
      const float p3 = (pb_ + 3 < end) ? __expf(accs[3]) : 0.f;
      lh += (p0 + p1) + (p2 + p3);
      union { unsigned int u[2]; short4i v; } pc;
      pc.u[0] = pk2bf(p0, p1);
      pc.u[1] = pk2bf(p2, p3);
      const short4i pf = pc.v;

      // ---- PV: o2[ob] += P * V (one b64 V-frag read per ob) ----
      const int vb = pq * 16 + l4 * 4;
#pragma unroll
      for (int ob = 0; ob < 8; ++ob) {
        const short4i vv =
            *(const short4i*)&VtU[cur][(ob * 16 + l16) * VSTR + vb];
        o2[ob] = mfma16bf16(pf, vv, o2[ob]);
      }

      if (pre) WRITE_TILE(cur ^ 1);   // idle buffer; visible after next barrier
    }
  }

  // ---- end of split: per-head denom (reduce over l4 groups) ----
  float lhr = lh;
  lhr += __shfl_xor(lhr, 16);
  lhr += __shfl_xor(lhr, 32);

  // slot = (b, s, pq); hq-waves write disjoint head ranges within the slot
  const size_t slot = ((size_t)(b * SPLITS + s) * 2 + pq) * NHEADS + hq * 16;
#pragma unroll
  for (int ob = 0; ob < 8; ++ob) {
    pacc[(slot + l4 * 4 + 0) * DIM + ob * 16 + l16] = f2bf(o2[ob][0]);
    pacc[(slot + l4 * 4 + 1) * DIM + ob * 16 + l16] = f2bf(o2[ob][1]);
    pacc[(slot + l4 * 4 + 2) * DIM + ob * 16 + l16] = f2bf(o2[ob][2]);
    pacc[(slot + l4 * 4 + 3) * DIM + ob * 16 + l16] = f2bf(o2[ob][3]);
  }
  if (lane < 16) pl[slot + lane] = lhr;
#undef LOADREGS
#undef WRITE_TILE
}

// combine partials -> attn[b][h*128+d]. grid=2048, block=128.
// No-max softmax => equal weights: out = sum(pacc)/sum(pl) over 32 slots.
__global__ __launch_bounds__(128) void combine_kernel(
    const float* __restrict__ pl, const unsigned short* __restrict__ pacc,
    float* __restrict__ attn)
{
  const int bh = blockIdx.x;
  const int b = bh >> 5, h = bh & 31;
  const int d = threadIdx.x;
  float L = 0.f, o = 0.f;
#pragma unroll 4
  for (int j = 0; j < SPLITS * 2; ++j) {
    const size_t idx = ((size_t)b * SPLITS * 2 + j) * NHEADS + h;
    L += pl[idx];
    o += bf2f(pacc[idx * DIM + d]);
  }
  attn[(size_t)b * HID + h * DIM + d] = o / L;
}

extern "C" void kernel_launch(void* const* d_in, const int* in_sizes, int n_in,
                              void* d_out, int out_size, void* d_ws, size_t ws_size,
                              hipStream_t stream) {
  const float* hidden   = (const float*)d_in[0];
  const float* wqkv     = (const float*)d_in[1];
  const float* wdense   = (const float*)d_in[2];
  const float* k_cache  = (const float*)d_in[3];
  const float* v_cache  = (const float*)d_in[4];
  const int* positions    = (const int*)d_in[5];   // integer inputs arrive as int32
  const int* block_tables = (const int*)d_in[6];
  const int* context_lens = (const int*)d_in[7];
  float* out = (float*)d_out;

  float* qkv  = (float*)d_ws;                 // 64*4352
  float* attn = qkv + 64 * QKV_N;             // 64*4096
  // union region: gp (GEMM partials, 16*64*4352 = 4.46M fl) aliases
  // pacc (bf16, 64*32*32*128 = 4.19M fl-equiv) + pl (65K fl); disjoint lifetimes.
  float* un   = attn + 64 * HID;
  float* gp   = un;
  unsigned short* pacc = (unsigned short*)un;
  float* pl   = un + (size_t)64 * SPLITS * 2 * NHEADS * DIM / 2;

  // 1) qkv = hidden @ wqkv  (bf16 MFMA, fused convert)
  gemm64_mfma<<<dim3(QKV_N / 64, KSPLIT), 256, 0, stream>>>(hidden, wqkv, gp, QKV_N, HID);
  reduce_parts<<<(64 * QKV_N) / 1024, 256, 0, stream>>>(gp, qkv, 64 * QKV_N);
  // 2) RoPE on q and k
  rope_kernel<<<64, 256, 0, stream>>>(qkv, positions);
  // 3) attention (MFMA flash-decoding, dbuf 1-barrier, global pq-partials)
  attn_kernel<<<dim3(64, SPLITS), 256, 0, stream>>>(qkv, k_cache, v_cache,
                                                    block_tables, context_lens, pl, pacc);
  combine_kernel<<<64 * NHEADS, 128, 0, stream>>>(pl, pacc, attn);
  // 4) out = attn @ wdense  (bf16 MFMA, fused convert)
  gemm64_mfma<<<dim3(HID / 64, KSPLIT), 256, 0, stream>>>(attn, wdense, gp, HID, HID);
  reduce_parts<<<(64 * HID) / 1024, 256, 0, stream>>>(gp, out, 64 * HID);
}

// Round 14
// 96.259 us; speedup vs baseline: 2.1469x; 1.1346x over previous
//
#include <hip/hip_runtime.h>
#include <hip/hip_bf16.h>
#include <cmath>

#define NHEADS 32
#define DIM 128
#define SPLITS 16
#define TILE 32
#define KSPLIT 8
#define QKV_N 4352
#define HID 4096

typedef __attribute__((ext_vector_type(4))) float f32x4;
typedef __attribute__((ext_vector_type(8))) short short8i;
typedef __attribute__((ext_vector_type(4))) short short4i;

__device__ __forceinline__ unsigned short f2bf(float x) {
  __hip_bfloat16 h = __float2bfloat16(x);   // RNE; HW cvt
  return *reinterpret_cast<unsigned short*>(&h);
}
__device__ __forceinline__ unsigned int pk2bf(float lo, float hi) {
  return (unsigned)f2bf(lo) | ((unsigned)f2bf(hi) << 16);
}

__device__ __forceinline__ f32x4 mfma16bf16(short4i a, short4i b, f32x4 c) {
#if __has_builtin(__builtin_amdgcn_mfma_f32_16x16x16bf16_1k)
  return __builtin_amdgcn_mfma_f32_16x16x16bf16_1k(a, b, c, 0, 0, 0);
#else
  asm volatile("v_mfma_f32_16x16x16_bf16 %0, %1, %2, %0"
               : "+v"(c) : "v"(a), "v"(b));
  return c;
#endif
}

// C[64,N] partials = A[64,K] @ W[K,N] via bf16 MFMA, fused fp32->bf16 convert.
// grid=(N/64, KSPLIT), block=256 (4 waves; wave w owns rows w*16..w*16+15).
// KSPLIT=8 -> 544/512 blocks: single co-residency round, HBM-bound.
__global__ __launch_bounds__(256, 4) void gemm64_mfma(
    const float* __restrict__ A, const float* __restrict__ W,
    float* __restrict__ P, int N, int K)
{
  __shared__ unsigned short Ab[64][40];   // bf16 A-tile [m][k]
  __shared__ unsigned short Wt[64][40];   // bf16 W-tile transposed [n][k]
  const int t = threadIdx.x;
  const int w = t >> 6, lane = t & 63;
  const int l4 = lane >> 4, l16 = lane & 15;
  const int n0 = blockIdx.x * 64;
  const int KS = K / KSPLIT;
  const int kbase = blockIdx.y * KS;

  const int ar = t >> 2, akq = t & 3;     // A staging: row 0..63, k-oct 0..3
  const int bn = t & 63, bkq = t >> 6;    // B staging: n 0..63, k-oct 0..3

  f32x4 acc[4];
#pragma unroll
  for (int i = 0; i < 4; ++i) acc[i] = (f32x4){0.f, 0.f, 0.f, 0.f};

  float4 a0, a1;
  float bw[8];

#define GLOAD(KC)                                                          \
  {                                                                        \
    const float* ap = A + (size_t)ar * K + kbase + (KC) + akq * 8;         \
    a0 = *(const float4*)ap;                                               \
    a1 = *(const float4*)(ap + 4);                                         \
    const float* wp = W + (size_t)(kbase + (KC) + bkq * 8) * N + n0 + bn;  \
    _Pragma("unroll")                                                      \
    for (int j = 0; j < 8; ++j) bw[j] = wp[(size_t)j * N];                 \
  }

#define SWRITE                                                             \
  {                                                                        \
    unsigned int ua[4] = {pk2bf(a0.x, a0.y), pk2bf(a0.z, a0.w),            \
                          pk2bf(a1.x, a1.y), pk2bf(a1.z, a1.w)};           \
    *(float4*)&Ab[ar][akq * 8] = *(float4*)ua;                             \
    unsigned int ub[4] = {pk2bf(bw[0], bw[1]), pk2bf(bw[2], bw[3]),        \
                          pk2bf(bw[4], bw[5]), pk2bf(bw[6], bw[7])};       \
    *(float4*)&Wt[bn][bkq * 8] = *(float4*)ub;                             \
  }

  GLOAD(0);
  SWRITE;
  __syncthreads();

  for (int kc = 0; kc < KS; kc += 32) {
    const bool pre = (kc + 32 < KS);
    if (pre) GLOAD(kc + 32);

    const short8i af = *(const short8i*)&Ab[w * 16 + l16][l4 * 8];
#pragma unroll
    for (int nt = 0; nt < 4; ++nt) {
      const short8i bf = *(const short8i*)&Wt[nt * 16 + l16][l4 * 8];
      acc[nt] = __builtin_amdgcn_mfma_f32_16x16x32_bf16(af, bf, acc[nt], 0, 0, 0);
    }

    __syncthreads();
    if (pre) {
      SWRITE;
      __syncthreads();
    }
  }

  float* base = P + (size_t)blockIdx.y * 64 * N + n0;
#pragma unroll
  for (int nt = 0; nt < 4; ++nt)
#pragma unroll
    for (int r = 0; r < 4; ++r)
      base[(size_t)(w * 16 + l4 * 4 + r) * N + nt * 16 + l16] = acc[nt][r];
#undef GLOAD
#undef SWRITE
}

// plain split-K reduce (used for gemm2 -> out)
__global__ __launch_bounds__(256) void reduce_parts(
    const float* __restrict__ P, float* __restrict__ C, int total)
{
  const int i = (blockIdx.x * 256 + threadIdx.x) * 4;
  if (i >= total) return;
  float4 s = *(const float4*)(P + i);
#pragma unroll
  for (int k = 1; k < KSPLIT; ++k) {
    const float4 v = *(const float4*)(P + (size_t)k * total + i);
    s.x += v.x; s.y += v.y; s.z += v.z; s.w += v.w;
  }
  *(float4*)(C + i) = s;
}

// Fused split-K reduce + RoPE for the qkv GEMM.
// Work item w in [0,560) per batch: w<528 -> rope float4-pair (row r, group g);
// w>=528 -> v-row float4 (plain reduce). grid = 64*560/256 = 140 blocks.
__global__ __launch_bounds__(256) void reduce_rope(
    const float* __restrict__ P, float* __restrict__ qkv,
    const int* __restrict__ positions)
{
  const int id = blockIdx.x * 256 + threadIdx.x;
  const int b = id / 560;
  const int w = id - b * 560;
  const int total = 64 * QKV_N;
  const size_t rbase = (size_t)b * QKV_N;

  if (w < 528) {
    const int r = w >> 4;                  // 0..32 (32 q heads, then k)
    const int g = w & 15;                  // float4 group within first half
    const int base = (r < 32) ? r * DIM : HID;
    const int c1 = base + g * 4;
    const int c2 = c1 + 64;
    float4 s1 = *(const float4*)(P + rbase + c1);
    float4 s2 = *(const float4*)(P + rbase + c2);
#pragma unroll
    for (int k = 1; k < KSPLIT; ++k) {
      const float4 v1 = *(const float4*)(P + (size_t)k * total + rbase + c1);
      const float4 v2 = *(const float4*)(P + (size_t)k * total + rbase + c2);
      s1.x += v1.x; s1.y += v1.y; s1.z += v1.z; s1.w += v1.w;
      s2.x += v2.x; s2.y += v2.y; s2.z += v2.z; s2.w += v2.w;
    }
    const float pos = (float)positions[b];
    float o1[4], o2[4];
    const float sv1[4] = {s1.x, s1.y, s1.z, s1.w};
    const float sv2[4] = {s2.x, s2.y, s2.z, s2.w};
#pragma unroll
    for (int j = 0; j < 4; ++j) {
      const int d = g * 4 + j;
      const float ex = (float)d * (1.0f / 64.0f);
      const float inv = 1.0f / powf(10000.0f, ex);
      const float ang = pos * inv;
      const float c = cosf(ang), sn = sinf(ang);
      o1[j] = sv1[j] * c - sv2[j] * sn;
      o2[j] = sv2[j] * c + sv1[j] * sn;
    }
    *(float4*)(qkv + rbase + c1) = make_float4(o1[0], o1[1], o1[2], o1[3]);
    *(float4*)(qkv + rbase + c2) = make_float4(o2[0], o2[1], o2[2], o2[3]);
  } else {
    const int c = HID + DIM + (w - 528) * 4;   // v row
    float4 s = *(const float4*)(P + rbase + c);
#pragma unroll
    for (int k = 1; k < KSPLIT; ++k) {
      const float4 v = *(const float4*)(P + (size_t)k * total + rbase + c);
      s.x += v.x; s.y += v.y; s.z += v.z; s.w += v.w;
    }
    *(float4*)(qkv + rbase + c) = s;
  }
}

// MFMA flash-decoding attention (exact R9 structure; pm dropped).
// grid=(64, SPLITS), block=256 (4 waves: hq=w>>1, pq=w&1).
__global__ __launch_bounds__(256, 4) void attn_kernel(
    const float* __restrict__ qkv,
    const float* __restrict__ k_cache, const float* __restrict__ v_cache,
    const int* __restrict__ block_tables, const int* __restrict__ context_lens,
    float* __restrict__ pl, float* __restrict__ pacc)
{
  const int b = blockIdx.x, s = blockIdx.y;
  const int t = threadIdx.x;
  const int w = t >> 6, lane = t & 63;
  const int hq = w >> 1, pq = w & 1;
  const int l4 = lane >> 4, l16 = lane & 15;
  const int ctx = context_lens[b];
  const int pos = ctx - 1;
  const int chunk = (ctx + SPLITS - 1) / SPLITS;
  const int start = s * chunk;
  const int end = min(start + chunk, ctx);
  const int nt = (end > start) ? ((end - start + TILE - 1) / TILE) : 0;

  __shared__ unsigned short KbU[32 * 128];   // 8 KB bf16 K, XOR-swizzled 16B units
  __shared__ unsigned short VtU[128 * 34];   // 8.5 KB bf16 V transposed [od][pos]
  __shared__ float red[2][64][36];           // 18.4 KB cross-pq reduction
  __shared__ int bt_lds[24];

  const float* qbase = qkv + (size_t)b * QKV_N;
  const int bt0 = start >> 4;
  if (t < 24) {
    const int idx = bt0 + t;
    bt_lds[t] = (idx < 256) ? block_tables[b * 256 + idx] : 0;
  }

  const float scale = 0.08838834764831845f;  // 1/sqrt(128)
  short8i qf[4];
  {
    const float* qp0 = qbase + (hq * 16 + l16) * DIM + l4 * 8;
#pragma unroll
    for (int ks = 0; ks < 4; ++ks) {
      const float4 a = *(const float4*)(qp0 + ks * 32);
      const float4 c = *(const float4*)(qp0 + ks * 32 + 4);
      union { unsigned int u[4]; short8i v; } qc;
      qc.u[0] = pk2bf(a.x * scale, a.y * scale);
      qc.u[1] = pk2bf(a.z * scale, a.w * scale);
      qc.u[2] = pk2bf(c.x * scale, c.y * scale);
      qc.u[3] = pk2bf(c.z * scale, c.w * scale);
      qf[ks] = qc.v;
    }
  }

  f32x4 o2[8];
#pragma unroll
  for (int i = 0; i < 8; ++i) o2[i] = (f32x4){0.f, 0.f, 0.f, 0.f};
  float lh = 0.f;

  float4 kreg[4], vreg[4];
  const int tk_sub = t >> 5;   // 0..7
  const int tk_col = t & 31;   // 0..31

#define LOADREGS(T0)                                                     \
  {                                                                      \
    _Pragma("unroll")                                                    \
    for (int j = 0; j < 4; ++j) {                                        \
      int gp_ = (T0) + j * 8 + tk_sub;                                   \
      if (gp_ > pos) gp_ = pos;                                          \
      const float* kp;                                                   \
      if (gp_ == pos) kp = qbase + HID;                                  \
      else {                                                             \
        const int blk = bt_lds[(gp_ >> 4) - bt0];                        \
        kp = k_cache + ((size_t)blk * 16 + (gp_ & 15)) * DIM;            \
      }                                                                  \
      kreg[j] = *(const float4*)(kp + tk_col * 4);                       \
    }                                                                    \
    int gv = (T0) + tk_col;                                              \
    if (gv > pos) gv = pos;                                              \
    const float* vp;                                                     \
    if (gv == pos) vp = qbase + HID + DIM;                               \
    else {                                                               \
      const int blk = bt_lds[(gv >> 4) - bt0];                           \
      vp = v_cache + ((size_t)blk * 16 + (gv & 15)) * DIM;               \
    }                                                                    \
    _Pragma("unroll")                                                    \
    for (int j = 0; j < 4; ++j)                                          \
      vreg[j] = *(const float4*)(vp + tk_sub * 16 + j * 4);              \
  }

#define WRITE_TILE                                                                     \
  {                                                                                    \
    _Pragma("unroll")                                                                  \
    for (int j = 0; j < 4; ++j) {                                                      \
      const int pl_ = j * 8 + tk_sub;                                                  \
      const int up = (tk_col >> 1) ^ (pl_ & 15);                                       \
      unsigned int lo = pk2bf(kreg[j].x, kreg[j].y);                                   \
      unsigned int hi = pk2bf(kreg[j].z, kreg[j].w);                                   \
      unsigned int* dst = (unsigned int*)&KbU[pl_ * 128 + up * 8 + (tk_col & 1) * 4];  \
      dst[0] = lo; dst[1] = hi;                                                        \
    }                                                                                  \
    _Pragma("unroll")                                                                  \
    for (int j = 0; j < 4; ++j) {                                                      \
      const int od0 = tk_sub * 16 + j * 4;                                             \
      VtU[(od0 + 0) * 34 + tk_col] = f2bf(vreg[j].x);                                  \
      VtU[(od0 + 1) * 34 + tk_col] = f2bf(vreg[j].y);                                  \
      VtU[(od0 + 2) * 34 + tk_col] = f2bf(vreg[j].z);                                  \
      VtU[(od0 + 3) * 34 + tk_col] = f2bf(vreg[j].w);                                  \
    }                                                                                  \
  }

  if (nt > 0) {
    __syncthreads();
    LOADREGS(start);
    WRITE_TILE;
    __syncthreads();

    for (int it = 0; it < nt; ++it) {
      const int t0 = start + it * TILE;
      const bool pre = (it + 1 < nt);
      if (pre) LOADREGS(t0 + TILE);

      f32x4 accs = {0.f, 0.f, 0.f, 0.f};
      const int rowK = pq * 16 + l16;
#pragma unroll
      for (int ks = 0; ks < 4; ++ks) {
        const int up = (l4 + ks * 4) ^ l16;
        const short8i kf = *(const short8i*)&KbU[rowK * 128 + up * 8];
        accs = __builtin_amdgcn_mfma_f32_16x16x32_bf16(kf, qf[ks], accs, 0, 0, 0);
      }

      const int pb_ = t0 + pq * 16 + l4 * 4;
      const float p0 = (pb_ + 0 < end) ? __expf(accs[0]) : 0.f;
      const float p1 = (pb_ + 1 < end) ? __expf(accs[1]) : 0.f;
      const float p2 = (pb_ + 2 < end) ? __expf(accs[2]) : 0.f;
      const float p3 = (pb_ + 3 < end) ? __expf(accs[3]) : 0.f;
      lh += (p0 + p1) + (p2 + p3);
      union { unsigned int u[2]; short4i v; } pc;
      pc.u[0] = pk2bf(p0, p1);
      pc.u[1] = pk2bf(p2, p3);
      const short4i pf = pc.v;

      const int vb = pq * 16 + l4 * 4;
#pragma unroll
      for (int ob = 0; ob < 8; ++ob) {
        const int rowV = ob * 16 + l16;
        union { unsigned int u[2]; short4i v; } vc;
        vc.u[0] = *(const unsigned int*)&VtU[rowV * 34 + vb];
        vc.u[1] = *(const unsigned int*)&VtU[rowV * 34 + vb + 2];
        o2[ob] = mfma16bf16(pf, vc.v, o2[ob]);
      }

      if (pre) {
        __syncthreads();
        WRITE_TILE;
        __syncthreads();
      }
    }
  }

  float lhr = lh;
  lhr += __shfl_xor(lhr, 16);
  lhr += __shfl_xor(lhr, 32);

  if (pq == 1) {
#pragma unroll
    for (int ob = 0; ob < 8; ++ob) *(f32x4*)&red[hq][lane][ob * 4] = o2[ob];
    red[hq][lane][32] = lhr;
  }
  __syncthreads();
  if (pq == 0) {
#pragma unroll
    for (int ob = 0; ob < 8; ++ob) {
      const f32x4 r4 = *(const f32x4*)&red[hq][lane][ob * 4];
      o2[ob] += r4;
    }
    lhr += red[hq][lane][32];
    const size_t sbase = (size_t)(b * SPLITS + s) * NHEADS + hq * 16;
#pragma unroll
    for (int ob = 0; ob < 8; ++ob) {
      pacc[(sbase + l4 * 4 + 0) * DIM + ob * 16 + l16] = o2[ob][0];
      pacc[(sbase + l4 * 4 + 1) * DIM + ob * 16 + l16] = o2[ob][1];
      pacc[(sbase + l4 * 4 + 2) * DIM + ob * 16 + l16] = o2[ob][2];
      pacc[(sbase + l4 * 4 + 3) * DIM + ob * 16 + l16] = o2[ob][3];
    }
    if (lane < 16) pl[sbase + lane] = lhr;
  }
#undef LOADREGS
#undef WRITE_TILE
}

// combine partials -> attn[b][h*128+d]. grid=2048, block=128.
// No-max softmax => equal split weights: out = sum(pacc)/sum(pl).
__global__ __launch_bounds__(128) void combine_kernel(
    const float* __restrict__ pl, const float* __restrict__ pacc,
    float* __restrict__ attn)
{
  const int bh = blockIdx.x;
  const int b = bh >> 5, h = bh & 31;
  const int d = threadIdx.x;
  float L = 0.f, o = 0.f;
#pragma unroll
  for (int s = 0; s < SPLITS; ++s) {
    const size_t idx = (size_t)(b * SPLITS + s) * NHEADS + h;
    L += pl[idx];
    o += pacc[idx * DIM + d];
  }
  attn[(size_t)b * HID + h * DIM + d] = o / L;
}

extern "C" void kernel_launch(void* const* d_in, const int* in_sizes, int n_in,
                              void* d_out, int out_size, void* d_ws, size_t ws_size,
                              hipStream_t stream) {
  const float* hidden   = (const float*)d_in[0];
  const float* wqkv     = (const float*)d_in[1];
  const float* wdense   = (const float*)d_in[2];
  const float* k_cache  = (const float*)d_in[3];
  const float* v_cache  = (const float*)d_in[4];
  const int* positions    = (const int*)d_in[5];   // integer inputs arrive as int32
  const int* block_tables = (const int*)d_in[6];
  const int* context_lens = (const int*)d_in[7];
  float* out = (float*)d_out;

  float* qkv  = (float*)d_ws;                 // 64*4352
  float* attn = qkv + 64 * QKV_N;             // 64*4096
  // union: gp (8*64*4352 = 2.23M fl) aliases pacc (4.19M fl) + pl (32K fl);
  // lifetimes disjoint (gemm1 -> before attn; gemm2 -> after combine).
  float* un   = attn + 64 * HID;
  float* gp   = un;
  float* pacc = un;
  float* pl   = pacc + (size_t)64 * SPLITS * NHEADS * DIM;

  // 1) qkv = hidden @ wqkv  (bf16 MFMA) + fused reduce+RoPE
  gemm64_mfma<<<dim3(QKV_N / 64, KSPLIT), 256, 0, stream>>>(hidden, wqkv, gp, QKV_N, HID);
  reduce_rope<<<140, 256, 0, stream>>>(gp, qkv, positions);
  // 2) attention (MFMA flash-decoding, R9 structure)
  attn_kernel<<<dim3(64, SPLITS), 256, 0, stream>>>(qkv, k_cache, v_cache,
                                                    block_tables, context_lens, pl, pacc);
  combine_kernel<<<64 * NHEADS, 128, 0, stream>>>(pl, pacc, attn);
  // 3) out = attn @ wdense  (bf16 MFMA) + reduce
  gemm64_mfma<<<dim3(HID / 64, KSPLIT), 256, 0, stream>>>(attn, wdense, gp, HID, HID);
  reduce_parts<<<(64 * HID) / 1024, 256, 0, stream>>>(gp, out, 64 * HID);
}

// Round 16
// 92.115 us; speedup vs baseline: 2.2435x; 1.0450x over previous
//
#include <hip/hip_runtime.h>
#include <hip/hip_bf16.h>
#include <cmath>

#define NHEADS 32
#define DIM 128
#define SPLITS 16
#define TILE 32
#define KSPLIT 8
#define QKV_N 4352
#define HID 4096

typedef __attribute__((ext_vector_type(4))) float f32x4;
typedef __attribute__((ext_vector_type(8))) short short8i;
typedef __attribute__((ext_vector_type(4))) short short4i;

__device__ __forceinline__ unsigned short f2bf(float x) {
  __hip_bfloat16 h = __float2bfloat16(x);   // RNE; HW cvt
  return *reinterpret_cast<unsigned short*>(&h);
}
__device__ __forceinline__ unsigned int pk2bf(float lo, float hi) {
  return (unsigned)f2bf(lo) | ((unsigned)f2bf(hi) << 16);
}
__device__ __forceinline__ float bf2f(unsigned short u) {
  unsigned int b = ((unsigned int)u) << 16;
  return __uint_as_float(b);
}

__device__ __forceinline__ f32x4 mfma16bf16(short4i a, short4i b, f32x4 c) {
#if __has_builtin(__builtin_amdgcn_mfma_f32_16x16x16bf16_1k)
  return __builtin_amdgcn_mfma_f32_16x16x16bf16_1k(a, b, c, 0, 0, 0);
#else
  asm volatile("v_mfma_f32_16x16x16_bf16 %0, %1, %2, %0"
               : "+v"(c) : "v"(a), "v"(b));
  return c;
#endif
}

// C[64,N] partials = A[64,K] @ W[K,N] via bf16 MFMA, fused fp32->bf16 convert.
// grid=(N/64, KSPLIT), block=256. KSPLIT=8 -> single co-residency round.
__global__ __launch_bounds__(256, 4) void gemm64_mfma(
    const float* __restrict__ A, const float* __restrict__ W,
    float* __restrict__ P, int N, int K)
{
  __shared__ unsigned short Ab[64][40];   // bf16 A-tile [m][k]
  __shared__ unsigned short Wt[64][40];   // bf16 W-tile transposed [n][k]
  const int t = threadIdx.x;
  const int w = t >> 6, lane = t & 63;
  const int l4 = lane >> 4, l16 = lane & 15;
  const int n0 = blockIdx.x * 64;
  const int KS = K / KSPLIT;
  const int kbase = blockIdx.y * KS;

  const int ar = t >> 2, akq = t & 3;     // A staging: row 0..63, k-oct 0..3
  const int bn = t & 63, bkq = t >> 6;    // B staging: n 0..63, k-oct 0..3

  f32x4 acc[4];
#pragma unroll
  for (int i = 0; i < 4; ++i) acc[i] = (f32x4){0.f, 0.f, 0.f, 0.f};

  float4 a0, a1;
  float bw[8];

#define GLOAD(KC)                                                          \
  {                                                                        \
    const float* ap = A + (size_t)ar * K + kbase + (KC) + akq * 8;         \
    a0 = *(const float4*)ap;                                               \
    a1 = *(const float4*)(ap + 4);                                         \
    const float* wp = W + (size_t)(kbase + (KC) + bkq * 8) * N + n0 + bn;  \
    _Pragma("unroll")                                                      \
    for (int j = 0; j < 8; ++j) bw[j] = wp[(size_t)j * N];                 \
  }

#define SWRITE                                                             \
  {                                                                        \
    unsigned int ua[4] = {pk2bf(a0.x, a0.y), pk2bf(a0.z, a0.w),            \
                          pk2bf(a1.x, a1.y), pk2bf(a1.z, a1.w)};           \
    *(float4*)&Ab[ar][akq * 8] = *(float4*)ua;                             \
    unsigned int ub[4] = {pk2bf(bw[0], bw[1]), pk2bf(bw[2], bw[3]),        \
                          pk2bf(bw[4], bw[5]), pk2bf(bw[6], bw[7])};       \
    *(float4*)&Wt[bn][bkq * 8] = *(float4*)ub;                             \
  }

  GLOAD(0);
  SWRITE;
  __syncthreads();

  for (int kc = 0; kc < KS; kc += 32) {
    const bool pre = (kc + 32 < KS);
    if (pre) GLOAD(kc + 32);

    const short8i af = *(const short8i*)&Ab[w * 16 + l16][l4 * 8];
#pragma unroll
    for (int nt = 0; nt < 4; ++nt) {
      const short8i bf = *(const short8i*)&Wt[nt * 16 + l16][l4 * 8];
      acc[nt] = __builtin_amdgcn_mfma_f32_16x16x32_bf16(af, bf, acc[nt], 0, 0, 0);
    }

    __syncthreads();
    if (pre) {
      SWRITE;
      __syncthreads();
    }
  }

  float* base = P + (size_t)blockIdx.y * 64 * N + n0;
#pragma unroll
  for (int nt = 0; nt < 4; ++nt)
#pragma unroll
    for (int r = 0; r < 4; ++r)
      base[(size_t)(w * 16 + l4 * 4 + r) * N + nt * 16 + l16] = acc[nt][r];
#undef GLOAD
#undef SWRITE
}

// plain split-K reduce (used for gemm2 -> out)
__global__ __launch_bounds__(256) void reduce_parts(
    const float* __restrict__ P, float* __restrict__ C, int total)
{
  const int i = (blockIdx.x * 256 + threadIdx.x) * 4;
  if (i >= total) return;
  float4 s = *(const float4*)(P + i);
#pragma unroll
  for (int k = 1; k < KSPLIT; ++k) {
    const float4 v = *(const float4*)(P + (size_t)k * total + i);
    s.x += v.x; s.y += v.y; s.z += v.z; s.w += v.w;
  }
  *(float4*)(C + i) = s;
}

// Fused split-K reduce + RoPE for the qkv GEMM. grid=140, block=256.
__global__ __launch_bounds__(256) void reduce_rope(
    const float* __restrict__ P, float* __restrict__ qkv,
    const int* __restrict__ positions)
{
  const int id = blockIdx.x * 256 + threadIdx.x;
  const int b = id / 560;
  const int w = id - b * 560;
  const int total = 64 * QKV_N;
  const size_t rbase = (size_t)b * QKV_N;

  if (w < 528) {
    const int r = w >> 4;                  // 0..32 (32 q heads, then k)
    const int g = w & 15;
    const int base = (r < 32) ? r * DIM : HID;
    const int c1 = base + g * 4;
    const int c2 = c1 + 64;
    float4 s1 = *(const float4*)(P + rbase + c1);
    float4 s2 = *(const float4*)(P + rbase + c2);
#pragma unroll
    for (int k = 1; k < KSPLIT; ++k) {
      const float4 v1 = *(const float4*)(P + (size_t)k * total + rbase + c1);
      const float4 v2 = *(const float4*)(P + (size_t)k * total + rbase + c2);
      s1.x += v1.x; s1.y += v1.y; s1.z += v1.z; s1.w += v1.w;
      s2.x += v2.x; s2.y += v2.y; s2.z += v2.z; s2.w += v2.w;
    }
    const float pos = (float)positions[b];
    float o1[4], o2[4];
    const float sv1[4] = {s1.x, s1.y, s1.z, s1.w};
    const float sv2[4] = {s2.x, s2.y, s2.z, s2.w};
#pragma unroll
    for (int j = 0; j < 4; ++j) {
      const int d = g * 4 + j;
      const float ex = (float)d * (1.0f / 64.0f);
      const float inv = 1.0f / powf(10000.0f, ex);
      const float ang = pos * inv;
      const float c = cosf(ang), sn = sinf(ang);
      o1[j] = sv1[j] * c - sv2[j] * sn;
      o2[j] = sv2[j] * c + sv1[j] * sn;
    }
    *(float4*)(qkv + rbase + c1) = make_float4(o1[0], o1[1], o1[2], o1[3]);
    *(float4*)(qkv + rbase + c2) = make_float4(o2[0], o2[1], o2[2], o2[3]);
  } else {
    const int c = HID + DIM + (w - 528) * 4;   // v row
    float4 s = *(const float4*)(P + rbase + c);
#pragma unroll
    for (int k = 1; k < KSPLIT; ++k) {
      const float4 v = *(const float4*)(P + (size_t)k * total + rbase + c);
      s.x += v.x; s.y += v.y; s.z += v.z; s.w += v.w;
    }
    *(float4*)(qkv + rbase + c) = s;
  }
}

// MFMA flash-decoding attention. grid=(64, SPLITS), block=256
// (4 waves: hq=w>>1 head-16-block, pq=w&1 pos-16-block).
// Single-buffered 17 KB LDS, per-pq global partials, packed b32 V^T writes.
// Block-table lookup: per-row (tiles are NOT 16-aligned; chunk arbitrary).
__global__ __launch_bounds__(256, 4) void attn_kernel(
    const float* __restrict__ qkv,
    const float* __restrict__ k_cache, const float* __restrict__ v_cache,
    const int* __restrict__ block_tables, const int* __restrict__ context_lens,
    float* __restrict__ pl, unsigned short* __restrict__ pacc)
{
  const int b = blockIdx.x, s = blockIdx.y;
  const int t = threadIdx.x;
  const int w = t >> 6, lane = t & 63;
  const int hq = w >> 1, pq = w & 1;
  const int l4 = lane >> 4, l16 = lane & 15;
  const int ctx = context_lens[b];
  const int pos = ctx - 1;
  const int chunk = (ctx + SPLITS - 1) / SPLITS;
  const int start = s * chunk;
  const int end = min(start + chunk, ctx);
  const int nt = (end > start) ? ((end - start + TILE - 1) / TILE) : 0;

  __shared__ unsigned short KbU[32 * 128];   // 8 KB bf16 K, XOR-swizzled 16B units
  __shared__ unsigned short VtU[128 * 34];   // 8.5 KB bf16 V^T [od][pos]
  __shared__ int bt_lds[24];

  const float* qbase = qkv + (size_t)b * QKV_N;
  const int bt0 = start >> 4;
  if (t < 24) {
    const int idx = bt0 + t;
    bt_lds[t] = (idx < 256) ? block_tables[b * 256 + idx] : 0;
  }

  const float scale = 0.08838834764831845f;  // 1/sqrt(128)
  short8i qf[4];
  {
    const float* qp0 = qbase + (hq * 16 + l16) * DIM + l4 * 8;
#pragma unroll
    for (int ks = 0; ks < 4; ++ks) {
      const float4 a = *(const float4*)(qp0 + ks * 32);
      const float4 c = *(const float4*)(qp0 + ks * 32 + 4);
      union { unsigned int u[4]; short8i v; } qc;
      qc.u[0] = pk2bf(a.x * scale, a.y * scale);
      qc.u[1] = pk2bf(a.z * scale, a.w * scale);
      qc.u[2] = pk2bf(c.x * scale, c.y * scale);
      qc.u[3] = pk2bf(c.z * scale, c.w * scale);
      qf[ks] = qc.v;
    }
  }

  f32x4 o2[8];
#pragma unroll
  for (int i = 0; i < 8; ++i) o2[i] = (f32x4){0.f, 0.f, 0.f, 0.f};
  float lh = 0.f;

  float4 kreg[4], vreg[4];
  const int tk_sub = t >> 5;                  // 0..7
  const int tk_col = t & 31;                  // 0..31
  const int vp2 = tk_sub + 8 * (tk_col >> 4); // V row-pair 0..15
  const int vd0 = (tk_col & 15) * 8;          // V dim base

  // K rows j*8+tk_sub (coalesced 512B rows); V row-pair {2*vp2, 2*vp2+1},
  // 8 dims each. Per-row block-table lookup (clamp-to-pos -> fresh path).
#define LOADREGS(T0)                                                     \
  {                                                                      \
    _Pragma("unroll")                                                    \
    for (int j = 0; j < 4; ++j) {                                        \
      int gp_ = (T0) + j * 8 + tk_sub;                                   \
      if (gp_ > pos) gp_ = pos;                                          \
      const float* kp;                                                   \
      if (gp_ == pos) kp = qbase + HID;                                  \
      else {                                                             \
        const int blk = bt_lds[(gp_ >> 4) - bt0];                        \
        kp = k_cache + ((size_t)blk * 16 + (gp_ & 15)) * DIM;            \
      }                                                                  \
      kreg[j] = *(const float4*)(kp + tk_col * 4);                       \
    }                                                                    \
    _Pragma("unroll")                                                    \
    for (int j = 0; j < 2; ++j) {                                        \
      int gv_ = (T0) + vp2 * 2 + j;                                      \
      if (gv_ > pos) gv_ = pos;                                          \
      const float* vp;                                                   \
      if (gv_ == pos) vp = qbase + HID + DIM;                            \
      else {                                                             \
        const int blk = bt_lds[(gv_ >> 4) - bt0];                        \
        vp = v_cache + ((size_t)blk * 16 + (gv_ & 15)) * DIM;            \
      }                                                                  \
      vreg[j * 2 + 0] = *(const float4*)(vp + vd0);                      \
      vreg[j * 2 + 1] = *(const float4*)(vp + vd0 + 4);                  \
    }                                                                    \
  }

#define WRITE_TILE                                                                     \
  {                                                                                    \
    _Pragma("unroll")                                                                  \
    for (int j = 0; j < 4; ++j) {                                                      \
      const int pl_ = j * 8 + tk_sub;                                                  \
      const int up = (tk_col >> 1) ^ (pl_ & 15);                                       \
      unsigned int* kd = (unsigned int*)&KbU[pl_ * 128 + up * 8 + (tk_col & 1) * 4];   \
      kd[0] = pk2bf(kreg[j].x, kreg[j].y);                                             \
      kd[1] = pk2bf(kreg[j].z, kreg[j].w);                                             \
    }                                                                                  \
    {                                                                                  \
      const int pc_ = vp2 * 2;                                                         \
      *(unsigned int*)&VtU[(vd0 + 0) * 34 + pc_] = pk2bf(vreg[0].x, vreg[2].x);        \
      *(unsigned int*)&VtU[(vd0 + 1) * 34 + pc_] = pk2bf(vreg[0].y, vreg[2].y);        \
      *(unsigned int*)&VtU[(vd0 + 2) * 34 + pc_] = pk2bf(vreg[0].z, vreg[2].z);        \
      *(unsigned int*)&VtU[(vd0 + 3) * 34 + pc_] = pk2bf(vreg[0].w, vreg[2].w);        \
      *(unsigned int*)&VtU[(vd0 + 4) * 34 + pc_] = pk2bf(vreg[1].x, vreg[3].x);        \
      *(unsigned int*)&VtU[(vd0 + 5) * 34 + pc_] = pk2bf(vreg[1].y, vreg[3].y);        \
      *(unsigned int*)&VtU[(vd0 + 6) * 34 + pc_] = pk2bf(vreg[1].z, vreg[3].z);        \
      *(unsigned int*)&VtU[(vd0 + 7) * 34 + pc_] = pk2bf(vreg[1].w, vreg[3].w);        \
    }                                                                                  \
  }

  if (nt > 0) {
    __syncthreads();             // bt_lds visible
    LOADREGS(start);
    WRITE_TILE;
    __syncthreads();

    for (int it = 0; it < nt; ++it) {
      const int t0 = start + it * TILE;
      const bool pre = (it + 1 < nt);
      if (pre) LOADREGS(t0 + TILE);   // vmem in flight under compute

      // ---- QK^T: D[pos,head] over this wave's quadrant ----
      f32x4 accs = {0.f, 0.f, 0.f, 0.f};
      const int rowK = pq * 16 + l16;
#pragma unroll
      for (int ks = 0; ks < 4; ++ks) {
        const int up = (l4 + ks * 4) ^ l16;
        const short8i kf = *(const short8i*)&KbU[rowK * 128 + up * 8];
        accs = __builtin_amdgcn_mfma_f32_16x16x32_bf16(kf, qf[ks], accs, 0, 0, 0);
      }

      // ---- exp (no max), mask, per-lane denom, pack P as PV A-frag ----
      const int pb_ = t0 + pq * 16 + l4 * 4;
      const float p0 = (pb_ + 0 < end) ? __expf(accs[0]) : 0.f;
      const float p1 = (pb_ + 1 < end) ? __expf(accs[1]) : 0.f;
      const float p2 = (pb_ + 2 < end) ? __expf(accs[2]) : 0.f;
      const float p3 = (pb_ + 3 < end) ? __expf(accs[3]) : 0.f;
      lh += (p0 + p1) + (p2 + p3);
      union { unsigned int u[2]; short4i v; } pc;
      pc.u[0] = pk2bf(p0, p1);
      pc.u[1] = pk2bf(p2, p3);
      const short4i pf = pc.v;

      // ---- PV: o2[ob] += P * V (b64 V^T frag reads) ----
      const int vb = pq * 16 + l4 * 4;
#pragma unroll
      for (int ob = 0; ob < 8; ++ob) {
        const int rowV = ob * 16 + l16;
        union { unsigned int u[2]; short4i v; } vc;
        vc.u[0] = *(const unsigned int*)&VtU[rowV * 34 + vb];
        vc.u[1] = *(const unsigned int*)&VtU[rowV * 34 + vb + 2];
        o2[ob] = mfma16bf16(pf, vc.v, o2[ob]);
      }

      if (pre) {
        __syncthreads();         // all waves done reading KbU/VtU
        WRITE_TILE;              // stage next tile
        __syncthreads();         // writes visible
      }
    }
  }

  // ---- end of split: per-head denom; each pq-wave writes its own slot ----
  float lhr = lh;
  lhr += __shfl_xor(lhr, 16);
  lhr += __shfl_xor(lhr, 32);

  const size_t slot = ((size_t)(b * SPLITS + s) * 2 + pq) * NHEADS + hq * 16;
#pragma unroll
  for (int ob = 0; ob < 8; ++ob) {
    pacc[(slot + l4 * 4 + 0) * DIM + ob * 16 + l16] = f2bf(o2[ob][0]);
    pacc[(slot + l4 * 4 + 1) * DIM + ob * 16 + l16] = f2bf(o2[ob][1]);
    pacc[(slot + l4 * 4 + 2) * DIM + ob * 16 + l16] = f2bf(o2[ob][2]);
    pacc[(slot + l4 * 4 + 3) * DIM + ob * 16 + l16] = f2bf(o2[ob][3]);
  }
  if (lane < 16) pl[slot + lane] = lhr;
#undef LOADREGS
#undef WRITE_TILE
}

// combine partials -> attn[b][h*128+d]. grid=2048, block=128.
// No-max softmax => equal weights: out = sum(pacc)/sum(pl) over 32 slots.
__global__ __launch_bounds__(128) void combine_kernel(
    const float* __restrict__ pl, const unsigned short* __restrict__ pacc,
    float* __restrict__ attn)
{
  const int bh = blockIdx.x;
  const int b = bh >> 5, h = bh & 31;
  const int d = threadIdx.x;
  float L = 0.f, o = 0.f;
#pragma unroll 4
  for (int j = 0; j < SPLITS * 2; ++j) {
    const size_t idx = ((size_t)b * SPLITS * 2 + j) * NHEADS + h;
    L += pl[idx];
    o += bf2f(pacc[idx * DIM + d]);
  }
  attn[(size_t)b * HID + h * DIM + d] = o / L;
}

extern "C" void kernel_launch(void* const* d_in, const int* in_sizes, int n_in,
                              void* d_out, int out_size, void* d_ws, size_t ws_size,
                              hipStream_t stream) {
  const float* hidden   = (const float*)d_in[0];
  const float* wqkv     = (const float*)d_in[1];
  const float* wdense   = (const float*)d_in[2];
  const float* k_cache  = (const float*)d_in[3];
  const float* v_cache  = (const float*)d_in[4];
  const int* positions    = (const int*)d_in[5];   // integer inputs arrive as int32
  const int* block_tables = (const int*)d_in[6];
  const int* context_lens = (const int*)d_in[7];
  float* out = (float*)d_out;

  float* qkv  = (float*)d_ws;                 // 64*4352
  float* attn = qkv + 64 * QKV_N;             // 64*4096
  // union: gp (8*64*4352 = 2.23M fl) aliases pacc bf16 (64*16*2*32*128 u16 =
  // 2.10M fl-equiv) + pl (65K fl); lifetimes disjoint.
  float* un   = attn + 64 * HID;
  float* gp   = un;
  unsigned short* pacc = (unsigned short*)un;
  float* pl   = un + (size_t)64 * SPLITS * 2 * NHEADS * DIM / 2;

  // 1) qkv = hidden @ wqkv  (bf16 MFMA) + fused reduce+RoPE
  gemm64_mfma<<<dim3(QKV_N / 64, KSPLIT), 256, 0, stream>>>(hidden, wqkv, gp, QKV_N, HID);
  reduce_rope<<<140, 256, 0, stream>>>(gp, qkv, positions);
  // 2) attention (MFMA flash-decoding, 17 KB LDS, per-pq global partials)
  attn_kernel<<<dim3(64, SPLITS), 256, 0, stream>>>(qkv, k_cache, v_cache,
                                                    block_tables, context_lens, pl, pacc);
  combine_kernel<<<64 * NHEADS, 128, 0, stream>>>(pl, pacc, attn);
  // 3) out = attn @ wdense  (bf16 MFMA) + reduce
  gemm64_mfma<<<dim3(HID / 64, KSPLIT), 256, 0, stream>>>(attn, wdense, gp, HID, HID);
  reduce_parts<<<(64 * HID) / 1024, 256, 0, stream>>>(gp, out, 64 * HID);
}